// Round 11
// baseline (87.635 us; speedup 1.0000x reference)
//
#include <hip/hip_runtime.h>
#include <hip/hip_bf16.h>
#include <stdint.h>

// Shapes (fixed): S=4, B=2, F=64, P=16, T=32, H=64, W=64, HID=32
#define THW   131072   // 32*64*64
#define NS    4
#define NB    2
#define NF    64
#define NP    16
#define HID   32
#define BN_EPS 1e-5f
#define PXT   256      // pixels per block tile (8 waves x 32-px MFMA tiles)

typedef short  bf16x8  __attribute__((ext_vector_type(8)));
typedef float  f32x16  __attribute__((ext_vector_type(16)));

union FragU { uint32_t u[4]; bf16x8 v; uint4 q; };

__device__ __forceinline__ uint32_t pk2(float a, float b) {
    __hip_bfloat162 h = __float22bfloat162_rn(make_float2(a, b));
    uint32_t r;
    __builtin_memcpy(&r, &h, sizeof(r));
    return r;
}
__device__ __forceinline__ float lo16(uint32_t u) { return __builtin_bit_cast(float, u << 16); }
__device__ __forceinline__ float hi16(uint32_t u) { return __builtin_bit_cast(float, u & 0xFFFF0000u); }

// R11 = R10 with 1KB-contiguous global streams (PXT 128->256) + bf16 LDS.
// Staging goes through registers: float4 load (64 lanes x 16B = 1KB per plane
// per instruction), cvt_pk into {f,f+1} bf16 pairs, ds_write_b128. LDS halves
// (fbuf = u32[2][32][256] = 64KB), and MFMA B-frags become DIRECT dword reads
// (frag.u[r] = fbuf[kb*8+hi*4+r][px]) — consume-side packing gone.
// Block = 512 threads = 8 waves; wave wv owns px tile wv*32..+31 (per-wave
// math identical to R9/R10). brev swizzle kept (R10: +10%).
__global__ __launch_bounds__(512, 2) void gssm_kernel(
    const float* __restrict__ feats, const float* __restrict__ ps,
    const float* __restrict__ w1,    const float* __restrict__ gamma,
    const float* __restrict__ beta,  const float* __restrict__ mean,
    const float* __restrict__ var,   const float* __restrict__ w2,
    float* __restrict__ out)
{
    __shared__ __align__(16) uint32_t fbuf[2][NF / 2][PXT];  // 65536 B (bf16 pairs {2fp,2fp+1})
    __shared__ __align__(16) uint32_t pbuf[NP / 2][PXT];     //  8192 B
    __shared__ __align__(16) uint32_t w1lds[32 * 44];        //  5632 B
    __shared__ float2 tbl[HID];                              //   256 B

    const int tid  = threadIdx.x;
    const int lane = tid & 63;
    const int wv   = tid >> 6;      // 0..7
    const int hi   = lane >> 5;
    const int ln   = lane & 31;

    // ---- stage w1 (BN-scale folded, bf16-packed) + tbl
    for (int t = tid; t < 1280; t += 512) {
        float2 v = ((const float2*)w1)[t];
        int o = t / 40, cp = t - o * 40;
        float sc = gamma[o] * rsqrtf(var[o] + BN_EPS);
        w1lds[o * 44 + (cp >> 3) * 8 + (cp & 7)] = pk2(v.x * sc, v.y * sc);
    }
    if (tid < HID) {
        float sc = gamma[tid] * rsqrtf(var[tid] + BN_EPS);
        tbl[tid] = make_float2(beta[tid] - mean[tid] * sc, w2[tid]);
    }

    const int tile = (int)(__brev((unsigned)blockIdx.x) >> 22);  // 10-bit bitrev, 1024 tiles
    const int px0g = tile * PXT;
    const int b    = px0g >> 17;               // THW = 2^17
    const int px0  = px0g & (THW - 1);

    const float* featsb = feats + (long)b * NF * THW + px0;
    const float* psb    = ps    + (long)b * NP * THW + px0;
    const long   sstr   = (long)NB * NF * THW;

    // wave wv stages f-pairs wv*4..wv*4+3; lane covers px 4*lane..4*lane+3
    auto stage_load = [&](int s, float4* v) {
        const float* base = featsb + (long)s * sstr;
        #pragma unroll
        for (int i = 0; i < 4; ++i) {
            const int fp = wv * 4 + i;
            v[2 * i]     = ((const float4*)(base + (long)(2 * fp)     * THW))[lane];
            v[2 * i + 1] = ((const float4*)(base + (long)(2 * fp + 1) * THW))[lane];
        }
    };
    auto stage_write = [&](const float4* v, int buf) {
        #pragma unroll
        for (int i = 0; i < 4; ++i) {
            const int fp = wv * 4 + i;
            uint4 w;
            w.x = pk2(v[2 * i].x, v[2 * i + 1].x);
            w.y = pk2(v[2 * i].y, v[2 * i + 1].y);
            w.z = pk2(v[2 * i].z, v[2 * i + 1].z);
            w.w = pk2(v[2 * i].w, v[2 * i + 1].w);
            *((uint4*)&fbuf[buf][fp][lane * 4]) = w;
        }
    };

    // ---- prologue: stage p (wave wv -> p-pair wv) + feats(s=0)
    {
        float4 pa = ((const float4*)(psb + (long)(2 * wv)     * THW))[lane];
        float4 pb = ((const float4*)(psb + (long)(2 * wv + 1) * THW))[lane];
        uint4 w;
        w.x = pk2(pa.x, pb.x);
        w.y = pk2(pa.y, pb.y);
        w.z = pk2(pa.z, pb.z);
        w.w = pk2(pa.w, pb.w);
        *((uint4*)&pbuf[wv][lane * 4]) = w;
        float4 v0[8];
        stage_load(0, v0);
        stage_write(v0, 0);
    }
    __syncthreads();

    // ---- hoist A fragments (w1*scale) and shift/w2 (PER-LANE, depends on hi)
    FragU afr[5];
    {
        const uint32_t abase = (uint32_t)(ln * 44 + hi * 4);
        #pragma unroll
        for (int k = 0; k < 5; ++k)
            afr[k].q = *((const uint4*)&w1lds[abase + k * 8]);
    }
    float sh[16], wo[16];
    #pragma unroll
    for (int r = 0; r < 16; ++r) {
        float2 t = tbl[(r & 3) + 8 * (r >> 2) + 4 * hi];
        sh[r] = t.x;
        wo[r] = t.y;
    }

    const int pxloc = wv * 32 + ln;   // this lane's pixel within the block tile

    // ---- p fragment: direct dword reads (pairs {8hi+2r, 8hi+2r+1})
    FragU bp;
    #pragma unroll
    for (int r = 0; r < 4; ++r)
        bp.u[r] = pbuf[hi * 4 + r][pxloc];

    auto consume = [&](int buf, FragU* pk) -> float {
        #pragma unroll
        for (int kb = 0; kb < 4; ++kb)
            #pragma unroll
            for (int r = 0; r < 4; ++r)
                pk[kb].u[r] = fbuf[buf][kb * 8 + hi * 4 + r][pxloc];
        f32x16 acc;
        #pragma unroll
        for (int r = 0; r < 16; ++r) acc[r] = 0.f;
        acc = __builtin_amdgcn_mfma_f32_32x32x16_bf16(afr[4].v, bp.v,    acc, 0, 0, 0);
        acc = __builtin_amdgcn_mfma_f32_32x32x16_bf16(afr[0].v, pk[0].v, acc, 0, 0, 0);
        acc = __builtin_amdgcn_mfma_f32_32x32x16_bf16(afr[1].v, pk[1].v, acc, 0, 0, 0);
        acc = __builtin_amdgcn_mfma_f32_32x32x16_bf16(afr[2].v, pk[2].v, acc, 0, 0, 0);
        acc = __builtin_amdgcn_mfma_f32_32x32x16_bf16(afr[3].v, pk[3].v, acc, 0, 0, 0);
        float pp[4] = {0.f, 0.f, 0.f, 0.f};
        #pragma unroll
        for (int r = 0; r < 16; ++r) {
            float h = fmaxf(acc[r] + sh[r], 0.f);
            pp[r & 3] = fmaf(h, wo[r], pp[r & 3]);
        }
        float part = (pp[0] + pp[1]) + (pp[2] + pp[3]);
        return part + __shfl_xor(part, 32);
    };

    FragU pk0[4], pk1[4], pk2f[4], pk3[4];
    float lg0, lg1, lg2, lg3;

    // ---- phase 0: loads(1) fly through consume(0); pack+write after
    {
        float4 v1[8];
        stage_load(1, v1);
        asm volatile("" ::: "memory");   // keep loads issued before consume
        lg0 = consume(0, pk0);
        stage_write(v1, 1);
    }
    __syncthreads();

    // ---- phase 1
    {
        float4 v2[8];
        stage_load(2, v2);
        asm volatile("" ::: "memory");
        lg1 = consume(1, pk1);
        stage_write(v2, 0);
    }
    __syncthreads();

    // ---- phase 2
    {
        float4 v3[8];
        stage_load(3, v3);
        asm volatile("" ::: "memory");
        lg2 = consume(0, pk2f);
        stage_write(v3, 1);
    }
    __syncthreads();

    // ---- phase 3
    lg3 = consume(1, pk3);

    // ---- softmax over 4 logits (b2 shift-invariant: skipped)
    const float m   = fmaxf(fmaxf(lg0, lg1), fmaxf(lg2, lg3));
    const float e0  = __expf(lg0 - m), e1 = __expf(lg1 - m);
    const float e2  = __expf(lg2 - m), e3 = __expf(lg3 - m);
    const float inv = 1.f / (e0 + e1 + e2 + e3);
    const float a0 = e0 * inv, a1 = e1 * inv, a2 = e2 * inv, a3 = e3 * inv;

    const int thw = px0 + pxloc;

    // ---- out[b][f][thw] = sum_s alpha_s * feats_s (from bf16 frags), f = k*16+hi*8+j
    float* ob = out + ((long)(b * NF + hi * 8)) * THW + thw;
    #pragma unroll
    for (int k = 0; k < 4; ++k)
        #pragma unroll
        for (int r = 0; r < 4; ++r) {
            float vlo = a0 * lo16(pk0[k].u[r]);
            float vhi = a0 * hi16(pk0[k].u[r]);
            vlo = fmaf(a1, lo16(pk1[k].u[r]), vlo);
            vhi = fmaf(a1, hi16(pk1[k].u[r]), vhi);
            vlo = fmaf(a2, lo16(pk2f[k].u[r]), vlo);
            vhi = fmaf(a2, hi16(pk2f[k].u[r]), vhi);
            vlo = fmaf(a3, lo16(pk3[k].u[r]), vlo);
            vhi = fmaf(a3, hi16(pk3[k].u[r]), vhi);
            ob[(long)(k * 16 + 2 * r)     * THW] = vlo;
            ob[(long)(k * 16 + 2 * r + 1) * THW] = vhi;
        }

    // ---- alpha[b][s][thw] at offset B*F*THW; hi=0 -> s=0,1 ; hi=1 -> s=2,3
    float* ab = out + (long)NB * NF * THW + ((long)(b * NS + hi * 2)) * THW + thw;
    ab[0]   = hi ? a2 : a0;
    ab[THW] = hi ? a3 : a1;
}

extern "C" void kernel_launch(void* const* d_in, const int* in_sizes, int n_in,
                              void* d_out, int out_size, void* d_ws, size_t ws_size,
                              hipStream_t stream) {
    const float* feats = (const float*)d_in[0];
    const float* ps    = (const float*)d_in[1];
    const float* w1    = (const float*)d_in[2];
    const float* gamma = (const float*)d_in[3];
    const float* beta  = (const float*)d_in[4];
    const float* mean  = (const float*)d_in[5];
    const float* var   = (const float*)d_in[6];
    const float* w2    = (const float*)d_in[7];
    float* out = (float*)d_out;

    dim3 grid(1024), block(512);   // 1024 blocks x 256 px = 262144 pixels
    hipLaunchKernelGGL(gssm_kernel, grid, block, 0, stream,
                       feats, ps, w1, gamma, beta, mean, var, w2, out);
}